// Round 11
// baseline (581.238 us; speedup 1.0000x reference)
//
#include <hip/hip_runtime.h>

#define B_ 8192
#define IN_ 1024
#define OUT_ 256
#define E_ 16
#define KTOP 3
#define H_ 512
#define MAXSLOTS 26624   // 24576 + 16*127 rounded up
#define NTILES 208       // MAXSLOTS / 128
#define NBLK 512         // mega-kernel grid: 2 blocks/CU x 256 CUs, all co-resident
#define GUNITS 2048      // gating units
#define P0UNITS 4609     // gating 2048 + W1t 2048 + W2t 512 + zero_row 1

typedef __bf16 bf16;
typedef __bf16 bf16x4 __attribute__((ext_vector_type(4)));
typedef __bf16 bf16x8 __attribute__((ext_vector_type(8)));
typedef float f32x4 __attribute__((ext_vector_type(4)));

// async global->LDS, 16B per lane. LDS dest must be wave-uniform base + lane*16.
__device__ __forceinline__ void async16(const bf16* g, bf16* l) {
    __builtin_amdgcn_global_load_lds(
        (const __attribute__((address_space(1))) void*)g,
        (__attribute__((address_space(3))) void*)l,
        16, 0, 0);
}

// ---------------- barrier state: 4 barriers x (16 spread counters + release flag) ----------------
// counter i of barrier b at bar[b*17*32 + i*32]; flag at bar[b*17*32 + 16*32].
__global__ void k_zero(int* __restrict__ bar) {
    for (int i = threadIdx.x; i < 4 * 17 * 32; i += 256) bar[i] = 0;
}

// grid-wide barrier: all NBLK blocks co-resident (guaranteed by launch bounds + LDS).
// Release/acquire at AGENT scope handles cross-XCD L2 writeback/invalidate.
__device__ __forceinline__ void gbar(int* bar, int b, int blk) {
    __syncthreads();
    if (threadIdx.x == 0) {
        int* base = bar + b * 17 * 32;
        __threadfence();
        __hip_atomic_fetch_add(base + (blk & 15) * 32, 1, __ATOMIC_RELEASE, __HIP_MEMORY_SCOPE_AGENT);
        if (blk == 0) {
            int sum;
            do {
                sum = 0;
                for (int i = 0; i < 16; i++)
                    sum += __hip_atomic_load(base + i * 32, __ATOMIC_RELAXED, __HIP_MEMORY_SCOPE_AGENT);
                if (sum < NBLK) __builtin_amdgcn_s_sleep(8);
            } while (sum < NBLK);
            __hip_atomic_store(base + 16 * 32, 1, __ATOMIC_RELEASE, __HIP_MEMORY_SCOPE_AGENT);
        } else {
            while (__hip_atomic_load(base + 16 * 32, __ATOMIC_ACQUIRE, __HIP_MEMORY_SCOPE_AGENT) == 0)
                __builtin_amdgcn_s_sleep(8);
        }
        __threadfence();
    }
    __syncthreads();
}

// ================================ mega-kernel: 5 phases, 4 global barriers ================================
__global__ __launch_bounds__(256, 2) void k_mega(
    const float* __restrict__ x, const float* __restrict__ wg,
    const float* __restrict__ W1, const float* __restrict__ b1,
    const float* __restrict__ W2, const float* __restrict__ b2,
    bf16* __restrict__ xbf, bf16* __restrict__ w1t, bf16* __restrict__ w2t,
    bf16* __restrict__ h, bf16* __restrict__ eout,
    int* __restrict__ row_ids, int* __restrict__ rowslot,
    int* __restrict__ top_idx, float* __restrict__ top_gate,
    int* __restrict__ counts, int* __restrict__ partial,
    float* __restrict__ partial_imp, int* __restrict__ tile_expert,
    bf16* __restrict__ zero_row, float* __restrict__ y, float* __restrict__ loss_out,
    int* __restrict__ bar) {
    __shared__ __align__(16) char smem[49152];   // 48 KB union across phases -> 2 blocks/CU by LDS
    int blk = blockIdx.x;
    int t = threadIdx.x;
    int lane = t & 63;

    // ================= phase 0: gating (self-staged wg) + W transposes + zero_row =================
    for (int u = blk; u < P0UNITS; u += NBLK) {
        if (u < GUNITS) {
            // ---- gating: 4 rows/unit; wg quarter staged as padded rows of 5 float4 (R7-proven) ----
            float4* swg4 = (float4*)smem;            // 20 KB
            int* lcnt = (int*)(smem + 20480);
            int row = u * 4 + (t >> 6);
            if (t < 16) lcnt[t] = 0;
            __syncthreads();
            float acc[16];
#pragma unroll
            for (int e = 0; e < 16; e++) acc[e] = 0.f;
            const float4* x4p = (const float4*)(x + (size_t)row * IN_);
            for (int q = 0; q < 4; q++) {
                const float4* src = (const float4*)(wg + q * 4096);
#pragma unroll
                for (int i = 0; i < 4; i++) {
                    int f = i * 256 + t;
                    swg4[(f >> 2) * 5 + (f & 3)] = src[f];
                }
                __syncthreads();
                float4 xv = x4p[q * 64 + lane];
                bf16x4 xb;
                xb[0] = (bf16)xv.x; xb[1] = (bf16)xv.y; xb[2] = (bf16)xv.z; xb[3] = (bf16)xv.w;
                *(bf16x4*)(xbf + (size_t)row * IN_ + (q * 64 + lane) * 4) = xb;
                float xs[4] = {xv.x, xv.y, xv.z, xv.w};
#pragma unroll
                for (int i = 0; i < 4; i++) {
                    int r = lane * 4 + i;
#pragma unroll
                    for (int e4 = 0; e4 < 4; e4++) {
                        float4 wv = swg4[r * 5 + e4];
                        acc[e4 * 4 + 0] += xs[i] * wv.x;
                        acc[e4 * 4 + 1] += xs[i] * wv.y;
                        acc[e4 * 4 + 2] += xs[i] * wv.z;
                        acc[e4 * 4 + 3] += xs[i] * wv.w;
                    }
                }
                __syncthreads();
            }
#pragma unroll
            for (int e = 0; e < 16; e++) {
#pragma unroll
                for (int s = 32; s > 0; s >>= 1) acc[e] += __shfl_xor(acc[e], s, 64);
            }
            if (lane == 0) {
                float v[16];
#pragma unroll
                for (int e = 0; e < 16; e++) v[e] = acc[e];
                int idx[KTOP];
                float val[KTOP];
#pragma unroll
                for (int k = 0; k < KTOP; k++) {
                    int best = 0;
                    float bv = v[0];
                    for (int e = 1; e < 16; e++) {
                        if (v[e] > bv) { bv = v[e]; best = e; }
                    }
                    idx[k] = best; val[k] = bv; v[best] = -1e30f;
                }
                float e1 = __expf(val[1] - val[0]);
                float e2 = __expf(val[2] - val[0]);
                float inv = 1.f / (1.f + e1 + e2);
                float g[KTOP] = {inv, e1 * inv, e2 * inv};
#pragma unroll
                for (int k = 0; k < KTOP; k++) {
                    top_idx[row * KTOP + k] = idx[k];
                    top_gate[row * KTOP + k] = g[k];
                    atomicAdd(&lcnt[idx[k]], 1);
                }
            }
            __syncthreads();
            if (t < 16) partial[u * 16 + t] = lcnt[t];
        } else if (u < 4608) {
            // ---- W transpose+convert: in [E][K][N] f32 -> out [E][N][K] bf16 ----
            __syncthreads();   // guard smem reuse across grid-stride units
            float (*tile)[65] = (float(*)[65])smem;   // 16.6 KB
            const float* in; bf16* out; int Kd, Nd, e, tk, tn;
            if (u < 4096) {
                int b1x = u - 2048;
                in = W1; out = w1t; Kd = IN_; Nd = H_;
                e = b1x >> 7; int tt = b1x & 127; tk = tt >> 3; tn = tt & 7;
            } else {
                int b2x = u - 4096;
                in = W2; out = w2t; Kd = H_; Nd = OUT_;
                e = b2x >> 5; int tt = b2x & 31; tk = tt >> 2; tn = tt & 3;
            }
            int r = t >> 6, c = t & 63;
            const float* src = in + ((size_t)e * Kd + tk * 64) * Nd + (size_t)tn * 64;
#pragma unroll
            for (int i = 0; i < 16; i++) {
                int rr = r + i * 4;
                tile[rr][c] = src[(size_t)rr * Nd + c];
            }
            __syncthreads();
            bf16* dst = out + ((size_t)e * Nd + tn * 64) * Kd + (size_t)tk * 64;
#pragma unroll
            for (int i = 0; i < 16; i++) {
                int rr = r + i * 4;
                dst[(size_t)rr * Kd + c] = (bf16)tile[c][rr];
            }
        } else {
            // ---- zero_row ----
#pragma unroll
            for (int i = 0; i < 4; i++) zero_row[t * 4 + i] = (bf16)0.f;
        }
    }
    gbar(bar, 0, blk);

    // ================= phase 1: scatterscan (blocks 0-15) + row_ids pads + tile_expert =================
    if (blk < 16) {
        struct SS {
            int segsum[16][16];
            int tote[16], spre[16], soff[16], lcnt[16];
            float limp[16];
        };
        SS* ss = (SS*)smem;
        int e = t & 15, seg = t >> 4;
        int s = 0;
        for (int i = 0; i < 128; i++) s += partial[(seg * 128 + i) * 16 + e];
        ss->segsum[seg][e] = s;
        if (t < 16) { ss->lcnt[t] = 0; ss->limp[t] = 0.f; }
        __syncthreads();
        if (t < 16) {
            int total = 0, pre = 0;
            for (int sg = 0; sg < 16; sg++) {
                int v = ss->segsum[sg][t];
                total += v;
                if (sg < blk) pre += v;
            }
            ss->tote[t] = total;
            ss->spre[t] = pre;
        }
        __syncthreads();
        if (t < 16) {
            int off = 0;
            for (int ee = 0; ee < t; ee++) off += (ss->tote[ee] + 127) & ~127;
            ss->soff[t] = off;
            if (blk == 0) counts[t] = ss->tote[t];
        }
        __syncthreads();
        if (blk == 0) {
            if (t < 16) {
                int off = ss->soff[t], pd = (ss->tote[t] + 127) & ~127;
                for (int tt = off >> 7; tt < (off + pd) >> 7; ++tt) tile_expert[tt] = t;
            }
            if (t == 0) {
                int tot = ss->soff[15] + ((ss->tote[15] + 127) & ~127);
                for (int tt = tot >> 7; tt < NTILES; ++tt) tile_expert[tt] = -1;
            }
        }
        {   // row_ids padding for expert == blk
            int pb = ss->soff[blk] + ss->tote[blk];
            int pe = ss->soff[blk] + ((ss->tote[blk] + 127) & ~127);
            for (int i = pb + t; i < pe; i += 256) row_ids[i] = -1;
        }
#pragma unroll
        for (int j = 0; j < 6; j++) {
            int gid = blk * 1536 + j * 256 + t;
            int ee = top_idx[gid];
            float g = top_gate[gid];
            int rank = atomicAdd(&ss->lcnt[ee], 1);
            atomicAdd(&ss->limp[ee], g);
            int slot = ss->soff[ee] + ss->spre[ee] + rank;
            row_ids[slot] = gid / KTOP;
            rowslot[gid] = slot;
        }
        __syncthreads();
        if (t < 16) partial_imp[blk * 16 + t] = ss->limp[t];
    }
    gbar(bar, 1, blk);

    // ================= phase 2: GEMM1 (R10-proven body; 832 units, n-fast for L3 sharing) =================
    {
        bf16* As = (bf16*)smem;              // 16 KB
        bf16* Bs = (bf16*)(smem + 16384);    // 16 KB
        int w = t >> 6;
        int wm = (w >> 1) * 64, wn = (w & 1) * 64;
        int lm = lane & 15, lq = lane >> 4;
        int rmod = (t >> 3) & 7;
        int cglob = (t & 7) ^ rmod;
        for (int u = blk; u < 832; u += NBLK) {
            int tilei = u >> 2;
            int e = tile_expert[tilei];
            if (e < 0) continue;
            int slot_base = tilei * 128;
            int nbase = (u & 3) * 128;
            const bf16* gA[4];
            const bf16* gB[4];
#pragma unroll
            for (int j = 0; j < 4; j++) {
                int m = j * 32 + (t >> 3);
                int rid = row_ids[slot_base + m];
                gA[j] = ((rid >= 0) ? xbf + (size_t)rid * IN_ : zero_row) + cglob * 8;
                gB[j] = w1t + ((size_t)e * H_ + nbase + m) * IN_ + cglob * 8;
            }
            f32x4 acc[4][4] = {};
            for (int k0 = 0; k0 < IN_; k0 += 64) {
#pragma unroll
                for (int j = 0; j < 4; j++) {
                    async16(gA[j] + k0, As + (j * 256 + t) * 8);
                    async16(gB[j] + k0, Bs + (j * 256 + t) * 8);
                }
                __syncthreads();
                const bf16x8* Av = (const bf16x8*)As;
                const bf16x8* Bv = (const bf16x8*)Bs;
#pragma unroll
                for (int ks = 0; ks < 2; ks++) {
                    int kc = ks * 4 + lq;
                    bf16x8 af[4], bfv[4];
#pragma unroll
                    for (int i = 0; i < 4; i++) {
                        int row = wm + i * 16 + lm;
                        af[i] = Av[row * 8 + (kc ^ (row & 7))];
                    }
#pragma unroll
                    for (int i = 0; i < 4; i++) {
                        int row = wn + i * 16 + lm;
                        bfv[i] = Bv[row * 8 + (kc ^ (row & 7))];
                    }
#pragma unroll
                    for (int mi = 0; mi < 4; mi++)
#pragma unroll
                        for (int ni = 0; ni < 4; ni++)
                            acc[mi][ni] = __builtin_amdgcn_mfma_f32_16x16x32_bf16(af[mi], bfv[ni], acc[mi][ni], 0, 0, 0);
                }
                __syncthreads();
            }
#pragma unroll
            for (int mi = 0; mi < 4; mi++) {
#pragma unroll
                for (int ni = 0; ni < 4; ni++) {
                    int colg = nbase + wn + ni * 16 + lm;
                    float bias = b1[e * H_ + colg];
#pragma unroll
                    for (int r = 0; r < 4; r++) {
                        int rowl = wm + mi * 16 + lq * 4 + r;
                        float v = acc[mi][ni][r] + bias;
                        v = v > 0.f ? v : 0.f;
                        h[(size_t)(slot_base + rowl) * H_ + colg] = (bf16)v;
                    }
                }
            }
        }
    }
    gbar(bar, 2, blk);

    // ================= phase 3: GEMM2 (BN=256, one unit per slot-tile, bf16 eout) =================
    {
        bf16* As = (bf16*)smem;              // 16 KB
        bf16* Bs = (bf16*)(smem + 16384);    // 32 KB
        int w = t >> 6;
        int wm = (w >> 1) * 64, wn = (w & 1) * 128;
        int lm = lane & 15, lq = lane >> 4;
        int rmod = (t >> 3) & 7;
        int cglob = (t & 7) ^ rmod;
        for (int u = blk; u < NTILES; u += NBLK) {
            int e = tile_expert[u];
            if (e < 0) continue;
            int slot_base = u * 128;
            const bf16* gA[4];
            const bf16* gB[8];
#pragma unroll
            for (int j = 0; j < 4; j++) {
                int m = j * 32 + (t >> 3);
                gA[j] = h + (size_t)(slot_base + m) * H_ + cglob * 8;
            }
#pragma unroll
            for (int j = 0; j < 8; j++) {
                int m = j * 32 + (t >> 3);
                gB[j] = w2t + ((size_t)e * OUT_ + m) * H_ + cglob * 8;
            }
            f32x4 acc[4][8] = {};
            for (int k0 = 0; k0 < H_; k0 += 64) {
#pragma unroll
                for (int j = 0; j < 4; j++) async16(gA[j] + k0, As + (j * 256 + t) * 8);
#pragma unroll
                for (int j = 0; j < 8; j++) async16(gB[j] + k0, Bs + (j * 256 + t) * 8);
                __syncthreads();
                const bf16x8* Av = (const bf16x8*)As;
                const bf16x8* Bv = (const bf16x8*)Bs;
#pragma unroll
                for (int ks = 0; ks < 2; ks++) {
                    int kc = ks * 4 + lq;
                    bf16x8 af[4], bfv[8];
#pragma unroll
                    for (int i = 0; i < 4; i++) {
                        int row = wm + i * 16 + lm;
                        af[i] = Av[row * 8 + (kc ^ (row & 7))];
                    }
#pragma unroll
                    for (int i = 0; i < 8; i++) {
                        int row = wn + i * 16 + lm;
                        bfv[i] = Bv[row * 8 + (kc ^ (row & 7))];
                    }
#pragma unroll
                    for (int mi = 0; mi < 4; mi++)
#pragma unroll
                        for (int ni = 0; ni < 8; ni++)
                            acc[mi][ni] = __builtin_amdgcn_mfma_f32_16x16x32_bf16(af[mi], bfv[ni], acc[mi][ni], 0, 0, 0);
                }
                __syncthreads();
            }
#pragma unroll
            for (int mi = 0; mi < 4; mi++) {
#pragma unroll
                for (int ni = 0; ni < 8; ni++) {
                    int colg = wn + ni * 16 + lm;
                    float bias = b2[e * OUT_ + colg];
#pragma unroll
                    for (int r = 0; r < 4; r++) {
                        int rowl = wm + mi * 16 + lq * 4 + r;
                        eout[(size_t)(slot_base + rowl) * OUT_ + colg] = (bf16)(acc[mi][ni][r] + bias);
                    }
                }
            }
        }
    }
    gbar(bar, 3, blk);

    // ================= phase 4: combine + loss =================
    for (int u = blk; u < B_ / 4 + 1; u += NBLK) {
        if (u == B_ / 4) {
            float* imp = (float*)smem;
            if (t < 16) {
                float s = 0.f;
#pragma unroll
                for (int b = 0; b < 16; b++) s += partial_imp[b * 16 + t];
                imp[t] = s;
            }
            __syncthreads();
            if (t == 0) {
                float si = 0.f, sl = 0.f;
                for (int e = 0; e < E_; e++) { si += imp[e]; sl += (float)counts[e]; }
                float mi_ = si / (float)E_, ml_ = sl / (float)E_;
                float vi = 0.f, vl = 0.f;
                for (int e = 0; e < E_; e++) {
                    float d = imp[e] - mi_; vi += d * d;
                    float d2 = (float)counts[e] - ml_; vl += d2 * d2;
                }
                vi /= (float)(E_ - 1); vl /= (float)(E_ - 1);
                *loss_out = vi / (mi_ * mi_ + 1e-10f) + vl / (ml_ * ml_ + 1e-10f);
            }
            __syncthreads();
            continue;
        }
        int b = u * 4 + (t >> 6);
        int s0 = rowslot[b * 3], s1 = rowslot[b * 3 + 1], s2 = rowslot[b * 3 + 2];
        float g0 = top_gate[b * 3], g1 = top_gate[b * 3 + 1], g2 = top_gate[b * 3 + 2];
        // agent-scope loads: eout aliases xbf whose lines this CU may hold stale from phase 2
        unsigned long long r0 = __hip_atomic_load(
            (const unsigned long long*)(eout + (size_t)s0 * OUT_ + lane * 4),
            __ATOMIC_RELAXED, __HIP_MEMORY_SCOPE_AGENT);
        unsigned long long r1 = __hip_atomic_load(
            (const unsigned long long*)(eout + (size_t)s1 * OUT_ + lane * 4),
            __ATOMIC_RELAXED, __HIP_MEMORY_SCOPE_AGENT);
        unsigned long long r2 = __hip_atomic_load(
            (const unsigned long long*)(eout + (size_t)s2 * OUT_ + lane * 4),
            __ATOMIC_RELAXED, __HIP_MEMORY_SCOPE_AGENT);
        bf16x4 v0 = *(bf16x4*)&r0;
        bf16x4 v1 = *(bf16x4*)&r1;
        bf16x4 v2 = *(bf16x4*)&r2;
        float4 r;
        r.x = g0 * (float)v0[0] + g1 * (float)v1[0] + g2 * (float)v2[0];
        r.y = g0 * (float)v0[1] + g1 * (float)v1[1] + g2 * (float)v2[1];
        r.z = g0 * (float)v0[2] + g1 * (float)v1[2] + g2 * (float)v2[2];
        r.w = g0 * (float)v0[3] + g1 * (float)v1[3] + g2 * (float)v2[3];
        ((float4*)y)[(size_t)b * 64 + lane] = r;
    }
}

extern "C" void kernel_launch(void* const* d_in, const int* in_sizes, int n_in,
                              void* d_out, int out_size, void* d_ws, size_t ws_size,
                              hipStream_t stream) {
    (void)in_sizes; (void)n_in; (void)out_size; (void)ws_size;
    const float* x = (const float*)d_in[0];
    const float* wgate = (const float*)d_in[1];
    const float* W1 = (const float*)d_in[2];
    const float* b1 = (const float*)d_in[3];
    const float* W2 = (const float*)d_in[4];
    const float* b2 = (const float*)d_in[5];
    float* y = (float*)d_out;  // [B*OUT] floats, then loss scalar at [B*OUT]

    char* p = (char*)d_ws;
    auto alloc = [&](size_t bytes) {
        char* q = p;
        p += (bytes + 255) & ~(size_t)255;
        return q;
    };
    bf16* xbf = (bf16*)alloc((size_t)B_ * IN_ * 2);          // 16 MB (dead after phase 2)
    bf16* w1t = (bf16*)alloc((size_t)E_ * H_ * IN_ * 2);     // 16 MB
    bf16* w2t = (bf16*)alloc((size_t)E_ * OUT_ * H_ * 2);    // 4 MB
    bf16* h = (bf16*)alloc((size_t)MAXSLOTS * H_ * 2);       // 27 MB
    int* row_ids = (int*)alloc((size_t)MAXSLOTS * 4);
    int* rowslot = (int*)alloc((size_t)B_ * KTOP * 4);
    int* top_idx = (int*)alloc((size_t)B_ * KTOP * 4);
    float* top_gate = (float*)alloc((size_t)B_ * KTOP * 4);
    int* counts = (int*)alloc(E_ * 4);
    int* partial = (int*)alloc((size_t)GUNITS * E_ * 4);     // 128 KB gating hists
    float* partial_imp = (float*)alloc(16 * E_ * 4);
    int* tile_expert = (int*)alloc(NTILES * 4);
    bf16* zero_row = (bf16*)alloc(IN_ * 2);
    int* bar = (int*)alloc(4 * 17 * 32 * 4);                 // barrier state
    // eout (13.5 MB bf16) aliases xbf (16 MB): xbf dead after phase 2; phase-4
    // readers use agent-scope loads (bypass possibly-stale per-XCD L2).
    bf16* eout = (bf16*)xbf;

    k_zero<<<dim3(1), dim3(256), 0, stream>>>(bar);
    k_mega<<<dim3(NBLK), dim3(256), 0, stream>>>(
        x, wgate, W1, b1, W2, b2, xbf, w1t, w2t, h, eout,
        row_ids, rowslot, top_idx, top_gate, counts, partial, partial_imp,
        tile_expert, zero_row, y, y + (size_t)B_ * OUT_, bar);
}

// Round 12
// 211.248 us; speedup vs baseline: 2.7515x; 2.7515x over previous
//
#include <hip/hip_runtime.h>

#define B_ 8192
#define IN_ 1024
#define OUT_ 256
#define E_ 16
#define KTOP 3
#define H_ 512
#define MAXSLOTS 26624   // 24576 + 16*127 rounded up
#define NTILES 208       // MAXSLOTS / 128
#define HBLK 16          // scatterscan blocks
#define GBLK 2048        // gating blocks

typedef __bf16 bf16;
typedef __bf16 bf16x4 __attribute__((ext_vector_type(4)));
typedef __bf16 bf16x8 __attribute__((ext_vector_type(8)));
typedef float f32x4 __attribute__((ext_vector_type(4)));

// async global->LDS, 16B per lane. LDS dest must be wave-uniform base + lane*16.
__device__ __forceinline__ void async16(const bf16* g, bf16* l) {
    __builtin_amdgcn_global_load_lds(
        (const __attribute__((address_space(1))) void*)g,
        (__attribute__((address_space(3))) void*)l,
        16, 0, 0);
}

// ================= stage1: gating(+hist, self-staged wg) + W transposes + inits, ONE launch =================
// blocks [0,2048): gating 4 rows each; [2048,4096): W1t; [4096,4608): W2t;
// [4608,4712): row_ids=-1; 4712: zero_row + tile_expert=-1.
__global__ __launch_bounds__(256) void k_stage1(
    const float* __restrict__ x, const float* __restrict__ wg,
    const float* __restrict__ W1, const float* __restrict__ W2,
    bf16* __restrict__ xbf, int* __restrict__ top_idx, float* __restrict__ top_gate,
    int* __restrict__ partial,
    bf16* __restrict__ w1t, bf16* __restrict__ w2t,
    int* __restrict__ row_ids, bf16* __restrict__ zero_row, int* __restrict__ tile_expert) {
    __shared__ __align__(16) float smem[5140];  // 20.6 KB: gating wg-stage (padded) / transpose tile
    int bx = blockIdx.x;
    int t = threadIdx.x;
    if (bx < GBLK) {
        // ---- gating: 4 rows/block; wg quarter [256j][16e] staged as padded rows of 5 float4 (R7-proven) ----
        int* lcnt = (int*)(smem + 5124);
        int lane = t & 63;
        int row = bx * 4 + (t >> 6);
        if (t < 16) lcnt[t] = 0;
        float acc[16];
#pragma unroll
        for (int e = 0; e < 16; e++) acc[e] = 0.f;
        const float4* x4p = (const float4*)(x + (size_t)row * IN_);
        float4* swg4 = (float4*)smem;
        for (int q = 0; q < 4; q++) {
            const float4* src = (const float4*)(wg + q * 4096);
#pragma unroll
            for (int i = 0; i < 4; i++) {
                int f = i * 256 + t;        // float4 idx within quarter [0,1024)
                swg4[(f >> 2) * 5 + (f & 3)] = src[f];
            }
            __syncthreads();
            float4 xv = x4p[q * 64 + lane];
            bf16x4 xb;
            xb[0] = (bf16)xv.x; xb[1] = (bf16)xv.y; xb[2] = (bf16)xv.z; xb[3] = (bf16)xv.w;
            *(bf16x4*)(xbf + (size_t)row * IN_ + (q * 64 + lane) * 4) = xb;
            float xs[4] = {xv.x, xv.y, xv.z, xv.w};
#pragma unroll
            for (int i = 0; i < 4; i++) {
                int r = lane * 4 + i;       // j-row within quarter
#pragma unroll
                for (int e4 = 0; e4 < 4; e4++) {
                    float4 wv = swg4[r * 5 + e4];
                    acc[e4 * 4 + 0] += xs[i] * wv.x;
                    acc[e4 * 4 + 1] += xs[i] * wv.y;
                    acc[e4 * 4 + 2] += xs[i] * wv.z;
                    acc[e4 * 4 + 3] += xs[i] * wv.w;
                }
            }
            __syncthreads();
        }
#pragma unroll
        for (int e = 0; e < 16; e++) {
#pragma unroll
            for (int s = 32; s > 0; s >>= 1) acc[e] += __shfl_xor(acc[e], s, 64);
        }
        if (lane == 0) {
            float v[16];
#pragma unroll
            for (int e = 0; e < 16; e++) v[e] = acc[e];
            int idx[KTOP];
            float val[KTOP];
#pragma unroll
            for (int k = 0; k < KTOP; k++) {
                int best = 0;
                float bv = v[0];
                for (int e = 1; e < 16; e++) {
                    if (v[e] > bv) { bv = v[e]; best = e; }
                }
                idx[k] = best; val[k] = bv; v[best] = -1e30f;
            }
            float e1 = __expf(val[1] - val[0]);
            float e2 = __expf(val[2] - val[0]);
            float inv = 1.f / (1.f + e1 + e2);
            float g[KTOP] = {inv, e1 * inv, e2 * inv};
#pragma unroll
            for (int k = 0; k < KTOP; k++) {
                top_idx[row * KTOP + k] = idx[k];
                top_gate[row * KTOP + k] = g[k];
                atomicAdd(&lcnt[idx[k]], 1);
            }
        }
        __syncthreads();
        if (t < 16) partial[bx * 16 + t] = lcnt[t];
        return;
    }
    if (bx >= 4608) {
        if (bx < 4712) {            // row_ids = -1 (104*256 == MAXSLOTS)
            row_ids[(bx - 4608) * 256 + t] = -1;
        } else {                    // zero_row + tile_expert
#pragma unroll
            for (int i = 0; i < 4; i++) zero_row[t * 4 + i] = (bf16)0.f;
            if (t < NTILES) tile_expert[t] = -1;
        }
        return;
    }
    // ---- W transpose+convert: in [E][K][N] f32 -> out [E][N][K] bf16 ----
    float (*tile)[65] = (float(*)[65])smem;   // 16.6 KB
    const float* in; bf16* out; int Kd, Nd, e, tk, tn;
    if (bx < 4096) {            // W1: 16 experts x (16 x 8) tiles
        int b1x = bx - 2048;
        in = W1; out = w1t; Kd = IN_; Nd = H_;
        e = b1x >> 7; int tt = b1x & 127; tk = tt >> 3; tn = tt & 7;
    } else {                    // W2: 16 experts x (8 x 4) tiles
        int b2x = bx - 4096;
        in = W2; out = w2t; Kd = H_; Nd = OUT_;
        e = b2x >> 5; int tt = b2x & 31; tk = tt >> 2; tn = tt & 3;
    }
    int r = t >> 6, c = t & 63;
    const float* src = in + ((size_t)e * Kd + tk * 64) * Nd + (size_t)tn * 64;
#pragma unroll
    for (int i = 0; i < 16; i++) {
        int rr = r + i * 4;
        tile[rr][c] = src[(size_t)rr * Nd + c];
    }
    __syncthreads();
    bf16* dst = out + ((size_t)e * Nd + tn * 64) * Kd + (size_t)tk * 64;
#pragma unroll
    for (int i = 0; i < 16; i++) {
        int rr = r + i * 4;
        dst[(size_t)rr * Kd + c] = (bf16)tile[c][rr];
    }
}

// ---------------- scatterscan: scan of 2048x16 partials + scatter, 16 blocks, zero global atomics ----------------
__global__ __launch_bounds__(256) void k_scatterscan(
    const int* __restrict__ top_idx, const float* __restrict__ top_gate,
    const int* __restrict__ partial,
    int* __restrict__ counts, int* __restrict__ tile_expert,
    int* __restrict__ row_ids, int* __restrict__ rowslot,
    float* __restrict__ partial_imp) {
    __shared__ int segsum[16][16];   // [seg][e]
    __shared__ int tote[16];
    __shared__ int sbase[16];
    __shared__ int lcnt[16];
    __shared__ float limp[16];
    int t = threadIdx.x;
    int blk = blockIdx.x;
    int e = t & 15, seg = t >> 4;    // 16 segs x 128 gating-chunks each
    int s = 0;
    for (int i = 0; i < 128; i++) s += partial[(seg * 128 + i) * 16 + e];
    segsum[seg][e] = s;
    if (t < 16) { lcnt[t] = 0; limp[t] = 0.f; }
    __syncthreads();
    if (t < 16) {
        int total = 0, pre = 0;
        for (int sg = 0; sg < 16; sg++) {
            int v = segsum[sg][t];
            total += v;
            if (sg < blk) pre += v;
        }
        tote[t] = total;
        segsum[0][t] = pre;
    }
    __syncthreads();
    if (t < 16) {
        int off = 0;
        for (int ee = 0; ee < 16; ee++) {
            if (ee == t) break;
            off += (tote[ee] + 127) & ~127;
        }
        sbase[t] = off + segsum[0][t];
        if (blk == 0) {
            counts[t] = tote[t];
            int pd = (tote[t] + 127) & ~127;
            for (int tt = off >> 7; tt < (off + pd) >> 7; ++tt) tile_expert[tt] = t;
        }
    }
    __syncthreads();
#pragma unroll
    for (int j = 0; j < 6; j++) {
        int gid = blk * 1536 + j * 256 + t;
        int ee = top_idx[gid];
        float g = top_gate[gid];
        int rank = atomicAdd(&lcnt[ee], 1);
        atomicAdd(&limp[ee], g);
        int slot = sbase[ee] + rank;
        row_ids[slot] = gid / KTOP;
        rowslot[gid] = slot;
    }
    __syncthreads();
    if (t < 16) partial_imp[blk * 16 + t] = limp[t];
}

// ---------------- GEMM1: R5/R10-proven exactly (BK=64, XOR swizzle, grid n-fast) ----------------
__global__ __launch_bounds__(256) void k_gemm1(
    const bf16* __restrict__ xbf, const bf16* __restrict__ w1t,
    const float* __restrict__ b1, const int* __restrict__ row_ids,
    const int* __restrict__ tile_expert, const bf16* __restrict__ zero_row,
    bf16* __restrict__ h) {
    int e = tile_expert[blockIdx.y];
    if (e < 0) return;
    int slot_base = blockIdx.y * 128;
    int nbase = blockIdx.x * 128;
    __shared__ __align__(16) bf16 As[128 * 64];  // 16 KB
    __shared__ __align__(16) bf16 Bs[128 * 64];  // 16 KB
    int t = threadIdx.x;
    int rmod = (t >> 3) & 7;
    int cglob = (t & 7) ^ rmod;
    const bf16* gA[4];
    const bf16* gB[4];
#pragma unroll
    for (int j = 0; j < 4; j++) {
        int m = j * 32 + (t >> 3);
        int rid = row_ids[slot_base + m];
        gA[j] = ((rid >= 0) ? xbf + (size_t)rid * IN_ : zero_row) + cglob * 8;
        gB[j] = w1t + ((size_t)e * H_ + nbase + m) * IN_ + cglob * 8;
    }
    int w = t >> 6, lane = t & 63;
    int wm = (w >> 1) * 64, wn = (w & 1) * 64;
    int lm = lane & 15, lq = lane >> 4;
    f32x4 acc[4][4] = {};
    for (int k0 = 0; k0 < IN_; k0 += 64) {
#pragma unroll
        for (int j = 0; j < 4; j++) {
            async16(gA[j] + k0, As + (j * 256 + t) * 8);
            async16(gB[j] + k0, Bs + (j * 256 + t) * 8);
        }
        __syncthreads();
        const bf16x8* Av = (const bf16x8*)As;
        const bf16x8* Bv = (const bf16x8*)Bs;
#pragma unroll
        for (int ks = 0; ks < 2; ks++) {
            int kc = ks * 4 + lq;
            bf16x8 af[4], bfv[4];
#pragma unroll
            for (int i = 0; i < 4; i++) {
                int row = wm + i * 16 + lm;
                af[i] = Av[row * 8 + (kc ^ (row & 7))];
            }
#pragma unroll
            for (int i = 0; i < 4; i++) {
                int row = wn + i * 16 + lm;
                bfv[i] = Bv[row * 8 + (kc ^ (row & 7))];
            }
#pragma unroll
            for (int mi = 0; mi < 4; mi++)
#pragma unroll
                for (int ni = 0; ni < 4; ni++)
                    acc[mi][ni] = __builtin_amdgcn_mfma_f32_16x16x32_bf16(af[mi], bfv[ni], acc[mi][ni], 0, 0, 0);
        }
        __syncthreads();
    }
#pragma unroll
    for (int mi = 0; mi < 4; mi++) {
#pragma unroll
        for (int ni = 0; ni < 4; ni++) {
            int colg = nbase + wn + ni * 16 + lm;
            float bias = b1[e * H_ + colg];
#pragma unroll
            for (int r = 0; r < 4; r++) {
                int rowl = wm + mi * 16 + lq * 4 + r;
                float v = acc[mi][ni][r] + bias;
                v = v > 0.f ? v : 0.f;
                h[(size_t)(slot_base + rowl) * H_ + colg] = (bf16)v;
            }
        }
    }
}

// ---------------- GEMM2: BN=256 (one block/tile), bf16 eout output (R10-proven) ----------------
__global__ __launch_bounds__(256) void k_gemm2(
    const bf16* __restrict__ h, const bf16* __restrict__ w2t,
    const float* __restrict__ b2, const int* __restrict__ tile_expert,
    bf16* __restrict__ eout) {
    int e = tile_expert[blockIdx.x];
    if (e < 0) return;
    int slot_base = blockIdx.x * 128;
    __shared__ __align__(16) bf16 As[128 * 64];   // 16 KB
    __shared__ __align__(16) bf16 Bs[256 * 64];   // 32 KB
    int t = threadIdx.x;
    int rmod = (t >> 3) & 7;
    int cglob = (t & 7) ^ rmod;
    const bf16* gA[4];
    const bf16* gB[8];
#pragma unroll
    for (int j = 0; j < 4; j++) {
        int m = j * 32 + (t >> 3);
        gA[j] = h + (size_t)(slot_base + m) * H_ + cglob * 8;
    }
#pragma unroll
    for (int j = 0; j < 8; j++) {
        int m = j * 32 + (t >> 3);
        gB[j] = w2t + ((size_t)e * OUT_ + m) * H_ + cglob * 8;
    }
    int w = t >> 6, lane = t & 63;
    int wm = (w >> 1) * 64, wn = (w & 1) * 128;
    int lm = lane & 15, lq = lane >> 4;
    f32x4 acc[4][8] = {};
    for (int k0 = 0; k0 < H_; k0 += 64) {
#pragma unroll
        for (int j = 0; j < 4; j++) async16(gA[j] + k0, As + (j * 256 + t) * 8);
#pragma unroll
        for (int j = 0; j < 8; j++) async16(gB[j] + k0, Bs + (j * 256 + t) * 8);
        __syncthreads();
        const bf16x8* Av = (const bf16x8*)As;
        const bf16x8* Bv = (const bf16x8*)Bs;
#pragma unroll
        for (int ks = 0; ks < 2; ks++) {
            int kc = ks * 4 + lq;
            bf16x8 af[4], bfv[8];
#pragma unroll
            for (int i = 0; i < 4; i++) {
                int row = wm + i * 16 + lm;
                af[i] = Av[row * 8 + (kc ^ (row & 7))];
            }
#pragma unroll
            for (int i = 0; i < 8; i++) {
                int row = wn + i * 16 + lm;
                bfv[i] = Bv[row * 8 + (kc ^ (row & 7))];
            }
#pragma unroll
            for (int mi = 0; mi < 4; mi++)
#pragma unroll
                for (int ni = 0; ni < 8; ni++)
                    acc[mi][ni] = __builtin_amdgcn_mfma_f32_16x16x32_bf16(af[mi], bfv[ni], acc[mi][ni], 0, 0, 0);
        }
        __syncthreads();
    }
#pragma unroll
    for (int mi = 0; mi < 4; mi++) {
#pragma unroll
        for (int ni = 0; ni < 8; ni++) {
            int colg = wn + ni * 16 + lm;
            float bias = b2[e * OUT_ + colg];
#pragma unroll
            for (int r = 0; r < 4; r++) {
                int rowl = wm + mi * 16 + lq * 4 + r;
                eout[(size_t)(slot_base + rowl) * OUT_ + colg] = (bf16)(acc[mi][ni][r] + bias);
            }
        }
    }
}

// ---------------- combine + loss (R10-proven) ----------------
__global__ __launch_bounds__(256) void k_combine(
    const bf16* __restrict__ eout, const int* __restrict__ rowslot,
    const float* __restrict__ top_gate, float* __restrict__ y,
    const float* __restrict__ partial_imp, const int* __restrict__ counts,
    float* __restrict__ loss_out) {
    int t = threadIdx.x;
    if (blockIdx.x == B_ / 4) {  // loss block
        __shared__ float imp[16];
        if (t < 16) {
            float s = 0.f;
#pragma unroll
            for (int b = 0; b < HBLK; b++) s += partial_imp[b * 16 + t];
            imp[t] = s;
        }
        __syncthreads();
        if (t == 0) {
            float si = 0.f, sl = 0.f;
            for (int e = 0; e < E_; e++) { si += imp[e]; sl += (float)counts[e]; }
            float mi_ = si / (float)E_, ml_ = sl / (float)E_;
            float vi = 0.f, vl = 0.f;
            for (int e = 0; e < E_; e++) {
                float d = imp[e] - mi_; vi += d * d;
                float d2 = (float)counts[e] - ml_; vl += d2 * d2;
            }
            vi /= (float)(E_ - 1); vl /= (float)(E_ - 1);
            *loss_out = vi / (mi_ * mi_ + 1e-10f) + vl / (ml_ * ml_ + 1e-10f);
        }
        return;
    }
    int b = blockIdx.x * 4 + (t >> 6);
    int lane = t & 63;
    int s0 = rowslot[b * 3], s1 = rowslot[b * 3 + 1], s2 = rowslot[b * 3 + 2];
    float g0 = top_gate[b * 3], g1 = top_gate[b * 3 + 1], g2 = top_gate[b * 3 + 2];
    bf16x4 v0 = *(const bf16x4*)(eout + (size_t)s0 * OUT_ + lane * 4);
    bf16x4 v1 = *(const bf16x4*)(eout + (size_t)s1 * OUT_ + lane * 4);
    bf16x4 v2 = *(const bf16x4*)(eout + (size_t)s2 * OUT_ + lane * 4);
    float4 r;
    r.x = g0 * (float)v0[0] + g1 * (float)v1[0] + g2 * (float)v2[0];
    r.y = g0 * (float)v0[1] + g1 * (float)v1[1] + g2 * (float)v2[1];
    r.z = g0 * (float)v0[2] + g1 * (float)v1[2] + g2 * (float)v2[2];
    r.w = g0 * (float)v0[3] + g1 * (float)v1[3] + g2 * (float)v2[3];
    ((float4*)y)[(size_t)b * 64 + lane] = r;
}

extern "C" void kernel_launch(void* const* d_in, const int* in_sizes, int n_in,
                              void* d_out, int out_size, void* d_ws, size_t ws_size,
                              hipStream_t stream) {
    (void)in_sizes; (void)n_in; (void)out_size; (void)ws_size;
    const float* x = (const float*)d_in[0];
    const float* wgate = (const float*)d_in[1];
    const float* W1 = (const float*)d_in[2];
    const float* b1 = (const float*)d_in[3];
    const float* W2 = (const float*)d_in[4];
    const float* b2 = (const float*)d_in[5];
    float* y = (float*)d_out;  // [B*OUT] floats, then loss scalar at [B*OUT]

    char* p = (char*)d_ws;
    auto alloc = [&](size_t bytes) {
        char* q = p;
        p += (bytes + 255) & ~(size_t)255;
        return q;
    };
    bf16* xbf = (bf16*)alloc((size_t)B_ * IN_ * 2);          // 16 MB (dead after gemm1)
    bf16* w1t = (bf16*)alloc((size_t)E_ * H_ * IN_ * 2);     // 16 MB
    bf16* w2t = (bf16*)alloc((size_t)E_ * OUT_ * H_ * 2);    // 4 MB
    bf16* h = (bf16*)alloc((size_t)MAXSLOTS * H_ * 2);       // 27 MB
    int* row_ids = (int*)alloc((size_t)MAXSLOTS * 4);
    int* rowslot = (int*)alloc((size_t)B_ * KTOP * 4);
    int* top_idx = (int*)alloc((size_t)B_ * KTOP * 4);
    float* top_gate = (float*)alloc((size_t)B_ * KTOP * 4);
    int* counts = (int*)alloc(E_ * 4);
    int* partial = (int*)alloc((size_t)GBLK * E_ * 4);       // 128 KB gating hists
    float* partial_imp = (float*)alloc(HBLK * E_ * 4);
    int* tile_expert = (int*)alloc(NTILES * 4);
    bf16* zero_row = (bf16*)alloc(IN_ * 2);
    // eout (13.5 MB bf16) aliases xbf (16 MB): xbf dead after gemm1.
    bf16* eout = (bf16*)xbf;

    k_stage1<<<dim3(4713), dim3(256), 0, stream>>>(
        x, wgate, W1, W2, xbf, top_idx, top_gate, partial, w1t, w2t,
        row_ids, zero_row, tile_expert);
    k_scatterscan<<<dim3(HBLK), dim3(256), 0, stream>>>(
        top_idx, top_gate, partial, counts, tile_expert, row_ids, rowslot, partial_imp);
    k_gemm1<<<dim3(H_ / 128, NTILES), dim3(256), 0, stream>>>(
        xbf, w1t, b1, row_ids, tile_expert, zero_row, h);
    k_gemm2<<<dim3(NTILES), dim3(256), 0, stream>>>(
        h, w2t, b2, tile_expert, eout);
    k_combine<<<dim3(B_ / 4 + 1), dim3(256), 0, stream>>>(
        eout, rowslot, top_gate, y, partial_imp, counts, y + (size_t)B_ * OUT_);
}